// Round 3
// baseline (16619.649 us; speedup 1.0000x reference)
//
#include <hip/hip_runtime.h>
#include <math.h>

// Problem constants
#define BB 32
#define LL 128
#define HH 1024
#define EE 512
#define G4 4096   // 4*H
#define NC 3

// ---------------- transpose: in (R x C) -> out (C x R) ----------------
__global__ __launch_bounds__(256) void transpose_k(const float* __restrict__ in,
                                                   float* __restrict__ out,
                                                   int R, int C) {
    __shared__ float tile[32][33];
    int c0 = blockIdx.x * 32, r0 = blockIdx.y * 32;
    int tx = threadIdx.x, ty = threadIdx.y;   // blockDim (32,8)
    #pragma unroll
    for (int i = 0; i < 32; i += 8)
        tile[ty + i][tx] = in[(size_t)(r0 + ty + i) * C + (c0 + tx)];
    __syncthreads();
    #pragma unroll
    for (int i = 0; i < 32; i += 8)
        out[(size_t)(c0 + ty + i) * R + (r0 + tx)] = tile[tx][ty + i];
}

// ---------------- input projection: gbuf[t][b][j] = emb[tok] @ WihT + b_ih + b_hh ----
// grid: (64 j-tiles, 128 t), block 256
__global__ __launch_bounds__(256) void proj_k(const int* __restrict__ Xtok,
                                              const float* __restrict__ emb,
                                              const float* __restrict__ Wt_ih, // E x 4096
                                              const float* __restrict__ b_ih,
                                              const float* __restrict__ b_hh,
                                              float* __restrict__ gbuf) {
    __shared__ float xs[32][256];
    int t = blockIdx.y;
    int j0 = blockIdx.x * 64;
    int tid = threadIdx.x;
    int col = j0 + (tid & 63);
    int bg = tid >> 6;              // 0..3, rows b = bg*8 .. bg*8+7
    float bias = b_ih[col] + b_hh[col];
    float acc[8];
    #pragma unroll
    for (int i = 0; i < 8; ++i) acc[i] = bias;

    for (int ec = 0; ec < 2; ++ec) {          // e-chunks of 256
        __syncthreads();
        #pragma unroll
        for (int ii = 0; ii < 8; ++ii) {
            int fi = tid + 256 * ii;          // 2048 float4 = 32x256 floats
            int b = fi >> 6, e4 = fi & 63;
            int tok = Xtok[b * LL + t];
            ((float4*)&xs[b][e4 * 4])[0] =
                ((const float4*)(emb + (size_t)tok * EE + ec * 256))[e4];
        }
        __syncthreads();
        #pragma unroll 4
        for (int e = 0; e < 256; ++e) {
            float w = Wt_ih[(size_t)(ec * 256 + e) * G4 + col];
            #pragma unroll
            for (int i = 0; i < 8; ++i) acc[i] += xs[bg * 8 + i][e] * w;
        }
    }
    #pragma unroll
    for (int i = 0; i < 8; ++i) {
        int b = bg * 8 + i;
        gbuf[((size_t)t * BB + b) * G4 + col] = acc[i];
    }
}

// ---------------- one LSTM step ----------------
// grid 256 WGs (each owns 4 n's across all 4 gates), block 256
__global__ __launch_bounds__(256) void lstm_step_k(const float* __restrict__ g_t,  // [32][4096]
                                                   const float* __restrict__ Wt_hh, // H x 4096
                                                   const float* __restrict__ h_in,
                                                   float* __restrict__ h_out,
                                                   float* __restrict__ c,
                                                   float* __restrict__ r_sum,
                                                   int do_rsum) {
    __shared__ float hs[32][260];   // stride 260 -> conflict-free 4-distinct-b reads
    __shared__ float g_lds[32][16];
    int tid = threadIdx.x;
    int n0 = blockIdx.x * 4;
    int col16 = tid & 15;
    int bq = tid >> 4;              // 0..15 ; handles b = bq and b = bq+16
    int gate = col16 >> 2, nl = col16 & 3;
    int j = gate * HH + n0 + nl;

    float acc0 = g_t[(size_t)bq * G4 + j];
    float acc1 = g_t[(size_t)(bq + 16) * G4 + j];

    for (int kc = 0; kc < 4; ++kc) {         // k-chunks of 256
        __syncthreads();
        #pragma unroll
        for (int ii = 0; ii < 8; ++ii) {
            int fi = tid + 256 * ii;          // 2048 float4 = 32x256 floats
            int b = fi >> 6, k4 = fi & 63;
            ((float4*)&hs[b][k4 * 4])[0] =
                ((const float4*)(h_in + (size_t)b * HH + kc * 256))[k4];
        }
        __syncthreads();
        int kbase = kc * 256;
        #pragma unroll 8
        for (int kk = 0; kk < 256; ++kk) {
            float w = Wt_hh[(size_t)(kbase + kk) * G4 + j];
            acc0 += hs[bq][kk] * w;
            acc1 += hs[bq + 16][kk] * w;
        }
    }
    g_lds[bq][col16] = acc0;
    g_lds[bq + 16][col16] = acc1;
    __syncthreads();

    if (tid < 128) {
        int b = tid & 31, n2 = tid >> 5;      // n2: 0..3
        float gi = g_lds[b][0 + n2];
        float gf = g_lds[b][4 + n2];
        float gg = g_lds[b][8 + n2];
        float go = g_lds[b][12 + n2];
        int n = n0 + n2;
        size_t idx = (size_t)b * HH + n;
        float c_old = c[idx];
        float si = 1.f / (1.f + expf(-gi));
        float sf = 1.f / (1.f + expf(-gf));
        float so = 1.f / (1.f + expf(-go));
        float c_new = sf * c_old + si * tanhf(gg);
        float h_new = so * tanhf(c_new);
        c[idx] = c_new;
        h_out[idx] = h_new;
        if (do_rsum) r_sum[idx] += h_new;
    }
}

// ---------------- h_star = tanh(W_p@r + W_x@h_n), one wave per (b,row) -------
__global__ __launch_bounds__(256) void hstar_k(const float* __restrict__ W_p,
                                               const float* __restrict__ W_x,
                                               const float* __restrict__ r,
                                               const float* __restrict__ h_n,
                                               float* __restrict__ h_star) {
    int wid = blockIdx.x * 4 + (threadIdx.x >> 6);   // 0..32767
    int lane = threadIdx.x & 63;
    int b = wid >> 10, row = wid & 1023;
    const float4* wp = (const float4*)(W_p + ((size_t)b * HH + row) * HH);
    const float4* wx = (const float4*)(W_x + ((size_t)b * HH + row) * HH);
    const float4* rv = (const float4*)(r + (size_t)b * HH);
    const float4* hv = (const float4*)(h_n + (size_t)b * HH);
    float s = 0.f;
    #pragma unroll
    for (int q = 0; q < 4; ++q) {
        int k4 = q * 64 + lane;
        float4 a = wp[k4], u = rv[k4];
        s += a.x * u.x + a.y * u.y + a.z * u.z + a.w * u.w;
        float4 a2 = wx[k4], v = hv[k4];
        s += a2.x * v.x + a2.y * v.y + a2.z * v.z + a2.w * v.w;
    }
    #pragma unroll
    for (int off = 32; off; off >>= 1) s += __shfl_down(s, off);
    if (lane == 0) h_star[(size_t)b * HH + row] = tanhf(s);
}

// ---------------- logits + mean NLL loss ----------------
__global__ __launch_bounds__(128) void loss_k(const float* __restrict__ h_star,
                                              const float* __restrict__ cls_W,
                                              const float* __restrict__ cls_b,
                                              const int* __restrict__ target,
                                              float* __restrict__ out) {
    __shared__ float lg[32][NC];
    __shared__ float red[32];
    int tid = threadIdx.x;
    if (tid < BB * NC) {
        int b = tid / NC, cc = tid % NC;
        float s = cls_b[cc];
        const float* hv = h_star + (size_t)b * HH;
        const float* wv = cls_W + (size_t)cc * HH;
        for (int k = 0; k < HH; ++k) s += hv[k] * wv[k];
        lg[b][cc] = s;
    }
    __syncthreads();
    if (tid < BB) {
        float l0 = lg[tid][0], l1 = lg[tid][1], l2 = lg[tid][2];
        float m = fmaxf(l0, fmaxf(l1, l2));
        float lse = m + logf(expf(l0 - m) + expf(l1 - m) + expf(l2 - m));
        red[tid] = lse - lg[tid][target[tid]];
    }
    __syncthreads();
    if (tid == 0) {
        float s = 0.f;
        for (int b = 0; b < BB; ++b) s += red[b];
        out[0] = s / (float)BB;
    }
}

// ---------------- workspace layout (bytes) ----------------
#define OFF_WT_IH  ((size_t)0)                    //  512*4096*4 =  8388608
#define OFF_WT_HH  ((size_t)8388608)              // 1024*4096*4 = 16777216
#define OFF_GBUF   ((size_t)25165824)             // 128*32*4096*4 = 67108864
#define OFF_H0     ((size_t)92274688)             // 32*1024*4 = 131072
#define OFF_H1     ((size_t)92405760)
#define OFF_C      ((size_t)92536832)
#define OFF_R      ((size_t)92667904)
#define OFF_HSTAR  ((size_t)92798976)

extern "C" void kernel_launch(void* const* d_in, const int* in_sizes, int n_in,
                              void* d_out, int out_size, void* d_ws, size_t ws_size,
                              hipStream_t stream) {
    const int*   X_pre  = (const int*)d_in[0];
    const int*   X_hyp  = (const int*)d_in[1];
    const int*   target = (const int*)d_in[2];
    const float* emb    = (const float*)d_in[3];
    const float* W_ih_A = (const float*)d_in[4];
    const float* W_hh_A = (const float*)d_in[5];
    const float* b_ih_A = (const float*)d_in[6];
    const float* b_hh_A = (const float*)d_in[7];
    const float* W_ih_B = (const float*)d_in[8];
    const float* W_hh_B = (const float*)d_in[9];
    const float* b_ih_B = (const float*)d_in[10];
    const float* b_hh_B = (const float*)d_in[11];
    // d_in[12..14] (W_y, W_h, w_attn) are dead: softmax over a size-1 axis -> alpha==1
    const float* W_p    = (const float*)d_in[15];
    const float* W_x    = (const float*)d_in[16];
    const float* cls_W  = (const float*)d_in[17];
    const float* cls_b  = (const float*)d_in[18];
    float* out = (float*)d_out;

    char* ws = (char*)d_ws;
    float* Wt_ih = (float*)(ws + OFF_WT_IH);
    float* Wt_hh = (float*)(ws + OFF_WT_HH);
    float* gbuf  = (float*)(ws + OFF_GBUF);
    float* h0    = (float*)(ws + OFF_H0);
    float* h1    = (float*)(ws + OFF_H1);
    float* cbuf  = (float*)(ws + OFF_C);
    float* rsum  = (float*)(ws + OFF_R);
    float* hstar = (float*)(ws + OFF_HSTAR);

    // zero h0, h1, c, r_sum (ws is poisoned 0xAA before every call)
    hipMemsetAsync(ws + OFF_H0, 0, (size_t)4 * BB * HH * 4, stream);

    dim3 tb(32, 8);
    // ---- phase A ----
    transpose_k<<<dim3(EE / 32, G4 / 32), tb, 0, stream>>>(W_ih_A, Wt_ih, G4, EE);
    transpose_k<<<dim3(HH / 32, G4 / 32), tb, 0, stream>>>(W_hh_A, Wt_hh, G4, HH);
    proj_k<<<dim3(64, LL), 256, 0, stream>>>(X_pre, emb, Wt_ih, b_ih_A, b_hh_A, gbuf);
    for (int s = 0; s < LL; ++s) {
        const float* hin  = (s & 1) ? h1 : h0;
        float*       hout = (s & 1) ? h0 : h1;
        lstm_step_k<<<256, 256, 0, stream>>>(gbuf + (size_t)s * BB * G4, Wt_hh,
                                             hin, hout, cbuf, rsum, 1);
    }
    // ---- phase B ----
    transpose_k<<<dim3(EE / 32, G4 / 32), tb, 0, stream>>>(W_ih_B, Wt_ih, G4, EE);
    transpose_k<<<dim3(HH / 32, G4 / 32), tb, 0, stream>>>(W_hh_B, Wt_hh, G4, HH);
    proj_k<<<dim3(64, LL), 256, 0, stream>>>(X_hyp, emb, Wt_ih, b_ih_B, b_hh_B, gbuf);
    for (int s = LL; s < 2 * LL; ++s) {
        const float* hin  = (s & 1) ? h1 : h0;
        float*       hout = (s & 1) ? h0 : h1;
        lstm_step_k<<<256, 256, 0, stream>>>(gbuf + (size_t)(s - LL) * BB * G4, Wt_hh,
                                             hin, hout, cbuf, rsum, 0);
    }
    // after step 255 (odd) the final h is in h0
    hstar_k<<<8192, 256, 0, stream>>>(W_p, W_x, rsum, h0, hstar);
    loss_k<<<1, 128, 0, stream>>>(hstar, cls_W, cls_b, target, out);
}